// Round 9
// baseline (167.327 us; speedup 1.0000x reference)
//
#include <hip/hip_runtime.h>

// Problem constants (static in the reference: D1=D2=32, ADD1=ADD2=16, BATCH=8)
constexpr int FOCK_DIM = 4656;   // m*(m+1)/2 with m=96, 2 photons
constexpr int N        = 1024;   // D1*D2 (32*32)
constexpr int B        = 8;      // batch

typedef float f32x4  __attribute__((ext_vector_type(4)));
typedef int   i32x4  __attribute__((ext_vector_type(4)));
// 4-byte-aligned variant for the scattered stores (run starts are only
// guaranteed dword-aligned; global_store_dwordx4 needs only 4 B alignment)
typedef float f32x4u __attribute__((ext_vector_type(4), aligned(4)));

// Structure of the fock map (from the reference construction):
//   fock_idx[i*32 + j] = T(16+i) + (32 + j - i),  T(a)=96a - a(a-1)/2
// => for fixed i, the 32 j-entries are CONSECUTIVE fock indices.
// So after a full zero-fill, the only writes needed are
//   out[b, fock_idx[ii], fock_idx[jj]] = in[b, ii, jj]
// and each thread's 4 consecutive jj (within a 32-run) hit 4 consecutive
// output columns -> dense 16 B stores, 128 B per 8 lanes.
__global__ __launch_bounds__(256) void live_scatter_kernel(
    const float* __restrict__ in,
    const int*   __restrict__ fock_idx,
    float*       __restrict__ out) {

    const int ii = blockIdx.x;            // input row 0..1023
    const int t  = threadIdx.x;           // owns cols 4t..4t+3

    const int r = fock_idx[ii];                                   // uniform
    const int c = reinterpret_cast<const i32x4*>(fock_idx)[t].x;  // run start

    const float* __restrict__ src = in  + (size_t)ii * N + 4 * t;
    float*       __restrict__ dst = out + ((size_t)r * FOCK_DIM + (size_t)c);

    #pragma unroll
    for (int b = 0; b < B; ++b) {
        const f32x4 v = *reinterpret_cast<const f32x4*>(src + (size_t)b * N * N);
        *reinterpret_cast<f32x4u*>(dst + (size_t)b * FOCK_DIM * FOCK_DIM) = v;
    }
}

extern "C" void kernel_launch(void* const* d_in, const int* in_sizes, int n_in,
                              void* d_out, int out_size, void* d_ws, size_t ws_size,
                              hipStream_t stream) {
    const float* in       = (const float*)d_in[0];   // [B, 1024, 1024] fp32
    const int*   fock_idx = (const int*)d_in[1];     // [1024] int32
    float*       out      = (float*)d_out;           // [B, 4656, 4656] fp32

    // Bulk zero at the runtime fill's proven 6.6-6.9 TB/s, then write only
    // the 33.5 MB of actually non-zero entries.
    hipMemsetAsync(out, 0, (size_t)out_size * sizeof(float), stream);
    live_scatter_kernel<<<N, 256, 0, stream>>>(in, fock_idx, out);
}